// Round 1
// baseline (380.414 us; speedup 1.0000x reference)
//
#include <hip/hip_runtime.h>
#include <math.h>
#include <stdint.h>

#define K_NN 16
#define TILE_C 1024

// ---------------------------------------------------------------------------
// k0: ch2m = polynomial(ch2, M1, M2); also zero d_out (harness poisons 0xAA)
// y1 = M1[0][0] + M1[0][1]*x2 + M1[1][0]*x1 + M1[1][1]*x1*x2  (B[i][j]=pi_i*pj_j)
// ---------------------------------------------------------------------------
__global__ void k0_prep(const float* __restrict__ ch2,
                        const float* __restrict__ M1,
                        const float* __restrict__ M2,
                        float* __restrict__ ch2m,
                        float* __restrict__ out, int N) {
    int i = blockIdx.x * blockDim.x + threadIdx.x;
    if (i == 0) out[0] = 0.0f;
    if (i < N) {
        float x1 = ch2[2 * i + 0];
        float x2 = ch2[2 * i + 1];
        float y1 = M1[0] + M1[1] * x2 + M1[2] * x1 + M1[3] * x1 * x2;
        float y2 = M2[0] + M2[1] * x2 + M2[2] * x1 + M2[3] * x1 * x2;
        ch2m[2 * i + 0] = y1;
        ch2m[2 * i + 1] = y2;
    }
}

// ---------------------------------------------------------------------------
// k1: chunked brute-force KNN. Grid = (N/256 query blocks, nchunks).
// Each thread = one query; sweeps its chunk's candidates (staged in LDS),
// maintains sorted top-16 (ascending dist; ties resolved by processing order
// = ascending candidate index, matching jax.lax.top_k stability).
// ---------------------------------------------------------------------------
__global__ __launch_bounds__(256) void k1_knn(const float* __restrict__ ch1,
                                              const float* __restrict__ ch2m,
                                              float* __restrict__ pd,
                                              int* __restrict__ pidx,
                                              int N, int nchunks) {
    __shared__ float2 sc[TILE_C];
    const int M = N / nchunks;
    const int chunk = blockIdx.y;
    const int cbase = chunk * M;
    const int q = blockIdx.x * 256 + threadIdx.x;
    const float q0 = ch1[2 * q + 0];
    const float q1 = ch1[2 * q + 1];

    float d[K_NN];
    int   id[K_NN];
#pragma unroll
    for (int p = 0; p < K_NN; ++p) { d[p] = INFINITY; id[p] = 0; }

    for (int t0 = 0; t0 < M; t0 += TILE_C) {
        const int tl = min(TILE_C, M - t0);
        __syncthreads();
        for (int t = threadIdx.x; t < tl; t += 256)
            sc[t] = ((const float2*)ch2m)[cbase + t0 + t];
        __syncthreads();

        for (int j = 0; j < tl; ++j) {
            float2 c = sc[j];
            float dx = q0 - c.x;
            float dy = q1 - c.y;
            float nd = dx * dx + dy * dy;
            if (nd < d[K_NN - 1]) {               // strict: tie keeps older (smaller idx)
                int ni = cbase + t0 + j;
                bool cc[K_NN];
#pragma unroll
                for (int p = 0; p < K_NN; ++p) cc[p] = nd < d[p];
#pragma unroll
                for (int p = K_NN - 1; p >= 1; --p) {
                    d[p]  = cc[p - 1] ? d[p - 1]  : (cc[p] ? nd : d[p]);
                    id[p] = cc[p - 1] ? id[p - 1] : (cc[p] ? ni : id[p]);
                }
                d[0]  = cc[0] ? nd : d[0];
                id[0] = cc[0] ? ni : id[0];
            }
        }
    }

    size_t ob = ((size_t)q * nchunks + chunk) * K_NN;
#pragma unroll
    for (int p = 0; p < K_NN; ++p) { pd[ob + p] = d[p]; pidx[ob + p] = id[p]; }
}

// ---------------------------------------------------------------------------
// k2: merge per-chunk sorted lists -> global sorted top-16 per query.
// Replay inserts in (chunk, pos) order: candidate indices are ascending among
// equal distances (chunk c's indices all < chunk c+1's; within-chunk ties
// already idx-ascending), so strict-less insert keeps exact top_k semantics.
// ---------------------------------------------------------------------------
__global__ __launch_bounds__(256) void k2_merge(const float* __restrict__ pd,
                                                const int* __restrict__ pidx,
                                                int* __restrict__ midx,
                                                int N, int nchunks) {
    int q = blockIdx.x * 256 + threadIdx.x;
    if (q >= N) return;

    float d[K_NN];
    int   id[K_NN];
#pragma unroll
    for (int p = 0; p < K_NN; ++p) { d[p] = INFINITY; id[p] = 0; }

    for (int c = 0; c < nchunks; ++c) {
        size_t ob = ((size_t)q * nchunks + c) * K_NN;
        for (int p = 0; p < K_NN; ++p) {
            float nd = pd[ob + p];
            if (!(nd < d[K_NN - 1])) break;       // chunk list is sorted ascending
            int ni = pidx[ob + p];
            bool cc[K_NN];
#pragma unroll
            for (int t = 0; t < K_NN; ++t) cc[t] = nd < d[t];
#pragma unroll
            for (int t = K_NN - 1; t >= 1; --t) {
                d[t]  = cc[t - 1] ? d[t - 1]  : (cc[t] ? nd : d[t]);
                id[t] = cc[t - 1] ? id[t - 1] : (cc[t] ? ni : id[t]);
            }
            d[0]  = cc[0] ? nd : d[0];
            id[0] = cc[0] ? ni : id[0];
        }
    }

#pragma unroll
    for (int p = 0; p < K_NN; ++p) midx[(size_t)q * K_NN + p] = id[p];
}

// ---------------------------------------------------------------------------
// k3: scrambled gather + log-sum-exp reduction.
// A[k,n] = midx[(k*(N/K) + n/K)*K + (n%K)]; distance recomputed vs ch1[n].
// out -= sum_n log( (1/N) * sum_k exp(-dist/ (2*sigma2^2) ) ), sigma2=1.5.
// ---------------------------------------------------------------------------
__global__ __launch_bounds__(256) void k3_final(const float* __restrict__ ch1,
                                                const float* __restrict__ ch2m,
                                                const int* __restrict__ midx,
                                                float* __restrict__ out, int N) {
    int n = blockIdx.x * 256 + threadIdx.x;
    float t = 0.0f;
    if (n < N) {
        int g = n / K_NN;
        int r = n % K_NN;
        float q0 = ch1[2 * n + 0];
        float q1 = ch1[2 * n + 1];
        float s = 0.0f;
        int stride = N / K_NN;
#pragma unroll
        for (int k = 0; k < K_NN; ++k) {
            int j = k * stride + g;
            int a = midx[(size_t)j * K_NN + r];
            float cx = ch2m[2 * a + 0];
            float cy = ch2m[2 * a + 1];
            float dx = q0 - cx;
            float dy = q1 - cy;
            // D_KL = 0.5*(dx^2+dy^2)/sigma2^2 = dist/4.5
            s += expf(-(dx * dx + dy * dy) * (1.0f / 4.5f));
        }
        float expD = s / (float)N;
        t = (expD != 0.0f) ? logf(expD) : 0.0f;
    }

    // block reduction (4 waves of 64)
    __shared__ float red[4];
#pragma unroll
    for (int off = 32; off > 0; off >>= 1) t += __shfl_down(t, off, 64);
    int lane = threadIdx.x & 63;
    int wv = threadIdx.x >> 6;
    if (lane == 0) red[wv] = t;
    __syncthreads();
    if (threadIdx.x == 0) {
        float v = red[0] + red[1] + red[2] + red[3];
        atomicAdd(out, -v);
    }
}

// ---------------------------------------------------------------------------
extern "C" void kernel_launch(void* const* d_in, const int* in_sizes, int n_in,
                              void* d_out, int out_size, void* d_ws, size_t ws_size,
                              hipStream_t stream) {
    const float* ch1 = (const float*)d_in[0];
    const float* ch2 = (const float*)d_in[1];
    const float* M1  = (const float*)d_in[2];
    const float* M2  = (const float*)d_in[3];
    float* out = (float*)d_out;
    const int N = in_sizes[0] / 2;   // 8192

    // pick chunk count that fits workspace (prefer 8: minimizes total
    // insert-maintenance work while keeping 256 workgroups resident)
    int nchunks = 8;
    while (nchunks > 1) {
        size_t need = (size_t)N * 2 * sizeof(float)                    // ch2m
                    + (size_t)N * nchunks * K_NN * (sizeof(float) + sizeof(int))
                    + (size_t)N * K_NN * sizeof(int);                  // midx
        if (need <= ws_size) break;
        nchunks >>= 1;
    }

    char* ws = (char*)d_ws;
    float* ch2m = (float*)ws;
    float* pd   = (float*)(ws + (size_t)N * 2 * sizeof(float));
    int*   pidx = (int*)((char*)pd + (size_t)N * nchunks * K_NN * sizeof(float));
    int*   midx = (int*)((char*)pidx + (size_t)N * nchunks * K_NN * sizeof(int));

    k0_prep<<<(N + 255) / 256, 256, 0, stream>>>(ch2, M1, M2, ch2m, out, N);

    dim3 g1(N / 256, nchunks);
    k1_knn<<<g1, 256, 0, stream>>>(ch1, ch2m, pd, pidx, N, nchunks);

    k2_merge<<<(N + 255) / 256, 256, 0, stream>>>(pd, pidx, midx, N, nchunks);

    k3_final<<<(N + 255) / 256, 256, 0, stream>>>(ch1, ch2m, midx, out, N);
}

// Round 2
// 171.702 us; speedup vs baseline: 2.2155x; 2.2155x over previous
//
#include <hip/hip_runtime.h>
#include <math.h>
#include <stdint.h>

#define K_NN 16
#define QB 8        // queries per block
#define CB 32       // chunk-threads per query
#define NPTS 8192
#define MSL (NPTS / CB)   // 256 candidates per slice (fits 8-bit tag)
#define WIN 64            // staged window of slice steps

// ---------------------------------------------------------------------------
// k0: ch2m = polynomial(ch2, M1, M2); also zero d_out (harness poisons 0xAA)
// ---------------------------------------------------------------------------
__global__ void k0_prep(const float* __restrict__ ch2,
                        const float* __restrict__ M1,
                        const float* __restrict__ M2,
                        float* __restrict__ ch2m,
                        float* __restrict__ out, int N) {
    int i = blockIdx.x * blockDim.x + threadIdx.x;
    if (i == 0) out[0] = 0.0f;
    if (i < N) {
        float x1 = ch2[2 * i + 0];
        float x2 = ch2[2 * i + 1];
        float y1 = M1[0] + M1[1] * x2 + M1[2] * x1 + M1[3] * x1 * x2;
        float y2 = M2[0] + M2[1] * x2 + M2[2] * x1 + M2[3] * x1 * x2;
        ch2m[2 * i + 0] = y1;
        ch2m[2 * i + 1] = y2;
    }
}

// ---------------------------------------------------------------------------
// k1: KNN with in-block chunking + in-LDS merge tree.
// Block = 256 threads = QB queries x CB chunk-threads. Each thread keeps a
// sorted top-16 of packed keys (dist_bits & ~0xFF) | slice_pos over its
// 256-candidate slice, then a 5-level pairwise merge tree produces the global
// sorted top-16 per query. Ties: smaller key = smaller dist then smaller pos;
// cross-chunk ties -> left (lower chunk = lower global idx).
// ---------------------------------------------------------------------------
__global__ __launch_bounds__(256) void k1_knn(const float* __restrict__ ch1,
                                              const float* __restrict__ ch2m,
                                              int* __restrict__ midx) {
    // union: staging (CB rows x (WIN+1) padded) fits inside merge buffer size
    __shared__ float2 sh[QB * CB * K_NN];   // 4096 float2 = 32 KB

    const int tid = threadIdx.x;
    const int q   = tid & (QB - 1);
    const int c   = tid >> 3;               // chunk id, [0, CB)
    const int qg  = blockIdx.x * QB + q;

    const float q0 = ch1[2 * qg + 0];
    const float q1 = ch1[2 * qg + 1];
    const float2* __restrict__ ch2m2 = (const float2*)ch2m;

    unsigned int key[K_NN];
#pragma unroll
    for (int p = 0; p < K_NN; ++p) key[p] = 0xFFFFFFFFu;

    const int srow = c * (WIN + 1);

    for (int t0 = 0; t0 < MSL; t0 += WIN) {
        __syncthreads();
        // stage window: points c*MSL + [t0, t0+WIN) for all CB chunks
        for (int e = tid; e < CB * WIN; e += 256) {
            int cc2 = e >> 6;               // e / WIN
            int tt  = e & (WIN - 1);
            sh[cc2 * (WIN + 1) + tt] = ch2m2[cc2 * MSL + t0 + tt];
        }
        __syncthreads();

#pragma unroll 4
        for (int tt = 0; tt < WIN; ++tt) {
            float2 cpt = sh[srow + tt];
            float dx = q0 - cpt.x;
            float dy = q1 - cpt.y;
            float nd = dx * dx + dy * dy;
            unsigned int nk = (__float_as_uint(nd) & 0xFFFFFF00u) | (unsigned)(t0 + tt);
            if (nk < key[K_NN - 1]) {
                bool cc[K_NN];
#pragma unroll
                for (int p = 0; p < K_NN; ++p) cc[p] = nk < key[p];
#pragma unroll
                for (int p = K_NN - 1; p >= 1; --p)
                    key[p] = cc[p - 1] ? key[p - 1] : (cc[p] ? nk : key[p]);
                key[0] = cc[0] ? nk : key[0];
            }
        }
    }

    // unpack: truncated dist (float) + global candidate idx, into merge buffer
    __syncthreads();
#pragma unroll
    for (int p = 0; p < K_NN; ++p) {
        float df = __uint_as_float(key[p] & 0xFFFFFF00u);
        int   gi = c * MSL + (int)(key[p] & 0xFFu);
        sh[(q * CB + c) * K_NN + p] = make_float2(df, __int_as_float(gi));
    }
    __syncthreads();

    // 5-level pairwise merge tree: (q,c) += (q,c+s), s = 1,2,4,8,16
#pragma unroll
    for (int lvl = 0; lvl < 5; ++lvl) {
        const int s = 1 << lvl;
        const bool active = ((c & (2 * s - 1)) == 0);
        float2 out[K_NN];
        if (active) {
            const float2* A = &sh[(q * CB + c) * K_NN];
            const float2* B = &sh[(q * CB + c + s) * K_NN];
            int ia = 0, ib = 0;
#pragma unroll
            for (int i = 0; i < K_NN; ++i) {
                float2 av = A[ia];
                float2 bv = B[ib];
                bool tb = bv.x < av.x;      // tie -> A (lower chunk/global idx)
                out[i] = tb ? bv : av;
                ia += tb ? 0 : 1;
                ib += tb ? 1 : 0;
            }
        }
        __syncthreads();
        if (active) {
#pragma unroll
            for (int i = 0; i < K_NN; ++i)
                sh[(q * CB + c) * K_NN + i] = out[i];
        }
        __syncthreads();
    }

    if (c == 0) {
#pragma unroll
        for (int p = 0; p < K_NN; ++p)
            midx[qg * K_NN + p] = __float_as_int(sh[(q * CB) * K_NN + p].y);
    }
}

// ---------------------------------------------------------------------------
// k3: scrambled gather + log-sum-exp reduction.
// A[k,n] = midx[(k*(N/K) + n/K)*K + (n%K)]; distance recomputed vs ch1[n].
// ---------------------------------------------------------------------------
__global__ __launch_bounds__(256) void k3_final(const float* __restrict__ ch1,
                                                const float* __restrict__ ch2m,
                                                const int* __restrict__ midx,
                                                float* __restrict__ out, int N) {
    int n = blockIdx.x * 256 + threadIdx.x;
    float t = 0.0f;
    if (n < N) {
        int g = n / K_NN;
        int r = n % K_NN;
        float q0 = ch1[2 * n + 0];
        float q1 = ch1[2 * n + 1];
        float s = 0.0f;
        int stride = N / K_NN;
#pragma unroll
        for (int k = 0; k < K_NN; ++k) {
            int j = k * stride + g;
            int a = midx[(size_t)j * K_NN + r];
            float cx = ch2m[2 * a + 0];
            float cy = ch2m[2 * a + 1];
            float dx = q0 - cx;
            float dy = q1 - cy;
            s += expf(-(dx * dx + dy * dy) * (1.0f / 4.5f));
        }
        float expD = s / (float)N;
        t = (expD != 0.0f) ? logf(expD) : 0.0f;
    }

    __shared__ float red[4];
#pragma unroll
    for (int off = 32; off > 0; off >>= 1) t += __shfl_down(t, off, 64);
    int lane = threadIdx.x & 63;
    int wv = threadIdx.x >> 6;
    if (lane == 0) red[wv] = t;
    __syncthreads();
    if (threadIdx.x == 0) {
        float v = red[0] + red[1] + red[2] + red[3];
        atomicAdd(out, -v);
    }
}

// ---------------------------------------------------------------------------
extern "C" void kernel_launch(void* const* d_in, const int* in_sizes, int n_in,
                              void* d_out, int out_size, void* d_ws, size_t ws_size,
                              hipStream_t stream) {
    const float* ch1 = (const float*)d_in[0];
    const float* ch2 = (const float*)d_in[1];
    const float* M1  = (const float*)d_in[2];
    const float* M2  = (const float*)d_in[3];
    float* out = (float*)d_out;
    const int N = in_sizes[0] / 2;   // 8192

    char* ws = (char*)d_ws;
    float* ch2m = (float*)ws;                                    // 64 KB
    int*   midx = (int*)(ws + (size_t)N * 2 * sizeof(float));    // 512 KB

    k0_prep<<<(N + 255) / 256, 256, 0, stream>>>(ch2, M1, M2, ch2m, out, N);

    k1_knn<<<N / QB, 256, 0, stream>>>(ch1, ch2m, midx);

    k3_final<<<(N + 255) / 256, 256, 0, stream>>>(ch1, ch2m, midx, out, N);
}

// Round 3
// 110.634 us; speedup vs baseline: 3.4385x; 1.5520x over previous
//
#include <hip/hip_runtime.h>
#include <math.h>
#include <stdint.h>

#define K_NN 16
#define NPTS 8192
#define TILE 1024          // candidates staged per LDS tile
#define WPB 4              // waves (= queries) per block

// ---------------------------------------------------------------------------
// k0: ch2m = polynomial(ch2, M1, M2); also zero d_out (harness poisons 0xAA)
// ---------------------------------------------------------------------------
__global__ void k0_prep(const float* __restrict__ ch2,
                        const float* __restrict__ M1,
                        const float* __restrict__ M2,
                        float* __restrict__ ch2m,
                        float* __restrict__ out, int N) {
    int i = blockIdx.x * blockDim.x + threadIdx.x;
    if (i == 0) out[0] = 0.0f;
    if (i < N) {
        float x1 = ch2[2 * i + 0];
        float x2 = ch2[2 * i + 1];
        float y1 = M1[0] + M1[1] * x2 + M1[2] * x1 + M1[3] * x1 * x2;
        float y2 = M2[0] + M2[1] * x2 + M2[2] * x1 + M2[3] * x1 * x2;
        ch2m[2 * i + 0] = y1;
        ch2m[2 * i + 1] = y2;
    }
}

// ---------------------------------------------------------------------------
// k1: wave-cooperative KNN. One wave per query. Top-16 lives distributed in
// lanes 0-15 as sorted packed keys (dist_bits & ~0x1FFF) | candidate_idx.
// Per step: 64 lanes score 64 candidates; v_cmp vs wave-uniform kth gives a
// free ballot; a uniform scalar loop replays only real insert events.
// Insert with a stale kth is a self-rejecting no-op (nothing shifts when
// snk >= lane15's key), so the filter is purely an optimization.
// Packing gives exact (dist, idx) tie order = jax.lax.top_k stability.
// ---------------------------------------------------------------------------
__global__ __launch_bounds__(256) void k1_knn(const float* __restrict__ ch1,
                                              const float* __restrict__ ch2m,
                                              int* __restrict__ midx) {
    __shared__ float2 sh[TILE];        // 8 KB

    const int tid  = threadIdx.x;
    const int lane = tid & 63;
    const int w    = tid >> 6;
    const int qg   = blockIdx.x * WPB + w;

    const float q0 = ch1[2 * qg + 0];
    const float q1 = ch1[2 * qg + 1];
    const float4* __restrict__ g4 = (const float4*)ch2m;

    unsigned key = 0xFFFFFFFFu;        // lane-distributed sorted list (lanes 0-15)
    unsigned kth = 0xFFFFFFFFu;        // wave-uniform copy of lane 15's key

    for (int tile = 0; tile < NPTS / TILE; ++tile) {
        __syncthreads();
#pragma unroll
        for (int e = 0; e < (TILE / 2) / 256; ++e)   // TILE float2 = TILE/2 float4
            ((float4*)sh)[e * 256 + tid] = g4[tile * (TILE / 2) + e * 256 + tid];
        __syncthreads();

        for (int t = 0; t < TILE / 64; ++t) {
            float2 c = sh[t * 64 + lane];
            float dx = q0 - c.x;
            float dy = q1 - c.y;
            float nd = dx * dx + dy * dy;
            unsigned nk = (__float_as_uint(nd) & 0xFFFFE000u)
                        | (unsigned)(tile * TILE + t * 64 + lane);
            unsigned long long m = __ballot(nk < kth);
            while (m) {
                int l = __ffsll(m) - 1;
                m &= m - 1;
                unsigned snk = __builtin_amdgcn_readlane(nk, l);
                if (snk < kth) {                       // uniform scalar branch
                    unsigned up = __shfl_up(key, 1, 64);
                    bool c1 = snk < key;
                    bool c0 = (lane > 0) && (snk < up);
                    unsigned nv = c0 ? up : snk;
                    key = c1 ? nv : key;
                    kth = __builtin_amdgcn_readlane(key, 15);
                }
            }
        }
    }

    if (lane < K_NN)
        midx[qg * K_NN + lane] = (int)(key & 0x1FFFu);
}

// ---------------------------------------------------------------------------
// k3: scrambled gather + log-sum-exp. One thread per (n,k) pair (131072).
// A[k,n] = midx[(k*(N/K) + n/K)*K + (n%K)]; distance recomputed exactly.
// Segmented shuffle reduce over the 16 k-lanes, then wave/block reduce.
// ---------------------------------------------------------------------------
__global__ __launch_bounds__(256) void k3_final(const float* __restrict__ ch1,
                                                const float* __restrict__ ch2m,
                                                const int* __restrict__ midx,
                                                float* __restrict__ out, int N) {
    int t = blockIdx.x * 256 + threadIdx.x;   // [0, N*K)
    int n = t >> 4;
    int k = t & 15;
    int g = n >> 4;          // n / K
    int r = n & 15;          // n % K

    int j = k * (N / K_NN) + g;
    int a = midx[j * K_NN + r];
    float dx = ch1[2 * n + 0] - ch2m[2 * a + 0];
    float dy = ch1[2 * n + 1] - ch2m[2 * a + 1];
    float term = expf(-(dx * dx + dy * dy) * (1.0f / 4.5f));

    // sum over k within each 16-lane group
#pragma unroll
    for (int off = 8; off; off >>= 1) term += __shfl_down(term, off, 16);

    float v = 0.0f;
    if (k == 0) {
        float expD = term / (float)N;
        v = (expD != 0.0f) ? logf(expD) : 0.0f;
    }
    // wave sum (contributions live at lanes 0,16,32,48)
#pragma unroll
    for (int off = 32; off; off >>= 1) v += __shfl_down(v, off, 64);

    __shared__ float red[4];
    int lane = threadIdx.x & 63;
    int wv = threadIdx.x >> 6;
    if (lane == 0) red[wv] = v;
    __syncthreads();
    if (threadIdx.x == 0)
        atomicAdd(out, -(red[0] + red[1] + red[2] + red[3]));
}

// ---------------------------------------------------------------------------
extern "C" void kernel_launch(void* const* d_in, const int* in_sizes, int n_in,
                              void* d_out, int out_size, void* d_ws, size_t ws_size,
                              hipStream_t stream) {
    const float* ch1 = (const float*)d_in[0];
    const float* ch2 = (const float*)d_in[1];
    const float* M1  = (const float*)d_in[2];
    const float* M2  = (const float*)d_in[3];
    float* out = (float*)d_out;
    const int N = in_sizes[0] / 2;   // 8192

    char* ws = (char*)d_ws;
    float* ch2m = (float*)ws;                                    // 64 KB
    int*   midx = (int*)(ws + (size_t)N * 2 * sizeof(float));    // 512 KB

    k0_prep<<<(N + 255) / 256, 256, 0, stream>>>(ch2, M1, M2, ch2m, out, N);

    k1_knn<<<N / WPB, 256, 0, stream>>>(ch1, ch2m, midx);

    k3_final<<<(N * K_NN) / 256, 256, 0, stream>>>(ch1, ch2m, midx, out, N);
}

// Round 4
// 108.449 us; speedup vs baseline: 3.5078x; 1.0201x over previous
//
#include <hip/hip_runtime.h>
#include <math.h>
#include <stdint.h>

#define K_NN 16
#define NPTS 8192
#define TILE 2048          // candidates staged per LDS tile (16 KB)
#define WPB 4              // waves (= queries) per block

// ---------------------------------------------------------------------------
// k1: wave-cooperative KNN, polynomial fused into staging.
// One wave per query. Top-16 = lane-distributed sorted packed keys
// (dist_bits & ~0x1FFF) | candidate_idx in lanes 0-15. Per step: 64 lanes
// score 128 candidates (float4 = 2 points/lane); ballot vs wave-uniform kth;
// uniform scalar loop replays only real insert events. Insert shift uses DPP
// row_shr:1 (top-16 sits in one 16-lane DPP row) -- ~25 cyc chain vs ~100 for
// ds_permute-based __shfl_up. Stale-kth inserts self-reject, so the ballot
// filter is purely an optimization. Packing = exact jax top_k tie order.
// ---------------------------------------------------------------------------
__global__ __launch_bounds__(256) void k1_knn(const float* __restrict__ ch1,
                                              const float* __restrict__ ch2,
                                              const float* __restrict__ M1,
                                              const float* __restrict__ M2,
                                              int* __restrict__ midx,
                                              float* __restrict__ out) {
    __shared__ float2 sh[TILE];        // 16 KB

    const int tid  = threadIdx.x;
    const int lane = tid & 63;
    const int w    = tid >> 6;
    const int qg   = blockIdx.x * WPB + w;

    if (blockIdx.x == 0 && tid == 0) out[0] = 0.0f;   // k3 atomics start from 0

    const float q0 = ch1[2 * qg + 0];
    const float q1 = ch1[2 * qg + 1];

    const float a0 = M1[0], a1 = M1[1], a2 = M1[2], a3 = M1[3];
    const float b0 = M2[0], b1 = M2[1], b2 = M2[2], b3 = M2[3];

    const float4* __restrict__ g4 = (const float4*)ch2;

    unsigned key = 0xFFFFFFFFu;        // lanes 0-15: sorted top-16 packed keys
    unsigned kth = 0xFFFFFFFFu;        // wave-uniform copy of lane 15's key

    for (int tile = 0; tile < NPTS / TILE; ++tile) {
        __syncthreads();
        // stage window with polynomial applied: TILE points = TILE/2 float4
#pragma unroll
        for (int e = 0; e < (TILE / 2) / 256; ++e) {
            float4 v = g4[tile * (TILE / 2) + e * 256 + tid];
            float px0 = a0 + a1 * v.y + v.x * (a2 + a3 * v.y);
            float py0 = b0 + b1 * v.y + v.x * (b2 + b3 * v.y);
            float px1 = a0 + a1 * v.w + v.z * (a2 + a3 * v.w);
            float py1 = b0 + b1 * v.w + v.z * (b2 + b3 * v.w);
            ((float4*)sh)[e * 256 + tid] = make_float4(px0, py0, px1, py1);
        }
        __syncthreads();

        const float4* s4 = (const float4*)sh;
        for (int t = 0; t < TILE / 128; ++t) {
            float4 c = s4[t * 64 + lane];
            int base = tile * TILE + (t * 64 + lane) * 2;
            float dx0 = q0 - c.x, dy0 = q1 - c.y;
            float dx1 = q0 - c.z, dy1 = q1 - c.w;
            float nd0 = dx0 * dx0 + dy0 * dy0;
            float nd1 = dx1 * dx1 + dy1 * dy1;
            unsigned nk0 = (__float_as_uint(nd0) & 0xFFFFE000u) | (unsigned)base;
            unsigned nk1 = (__float_as_uint(nd1) & 0xFFFFE000u) | (unsigned)(base + 1);
            unsigned long long m0 = __ballot(nk0 < kth);
            unsigned long long m1 = __ballot(nk1 < kth);

            while (m0) {
                int l = __ffsll((unsigned long long)m0) - 1;
                m0 &= m0 - 1;
                unsigned snk = (unsigned)__builtin_amdgcn_readlane((int)nk0, l);
                if (snk < kth) {                      // uniform scalar branch
                    unsigned up = (unsigned)__builtin_amdgcn_update_dpp(
                        0, (int)key, 0x111, 0xF, 0xF, false);   // row_shr:1
                    bool c1 = snk < key;
                    unsigned nv = (snk < up) ? up : snk;
                    key = c1 ? nv : key;
                    kth = (unsigned)__builtin_amdgcn_readlane((int)key, 15);
                }
            }
            while (m1) {
                int l = __ffsll((unsigned long long)m1) - 1;
                m1 &= m1 - 1;
                unsigned snk = (unsigned)__builtin_amdgcn_readlane((int)nk1, l);
                if (snk < kth) {
                    unsigned up = (unsigned)__builtin_amdgcn_update_dpp(
                        0, (int)key, 0x111, 0xF, 0xF, false);
                    bool c1 = snk < key;
                    unsigned nv = (snk < up) ? up : snk;
                    key = c1 ? nv : key;
                    kth = (unsigned)__builtin_amdgcn_readlane((int)key, 15);
                }
            }
        }
    }

    if (lane < K_NN)
        midx[qg * K_NN + lane] = (int)(key & 0x1FFFu);
}

// ---------------------------------------------------------------------------
// k3: scrambled gather + log-sum-exp. One thread per (n,k) pair (131072).
// A[k,n] = midx[(k*(N/K) + n/K)*K + (n%K)]; distance recomputed exactly with
// the polynomial applied on the fly (identity for this M1/M2 -> bit-exact).
// ---------------------------------------------------------------------------
__global__ __launch_bounds__(256) void k3_final(const float* __restrict__ ch1,
                                                const float* __restrict__ ch2,
                                                const float* __restrict__ M1,
                                                const float* __restrict__ M2,
                                                const int* __restrict__ midx,
                                                float* __restrict__ out, int N) {
    const float a0 = M1[0], a1 = M1[1], a2 = M1[2], a3 = M1[3];
    const float b0 = M2[0], b1 = M2[1], b2 = M2[2], b3 = M2[3];

    int t = blockIdx.x * 256 + threadIdx.x;   // [0, N*K)
    int n = t >> 4;
    int k = t & 15;
    int g = n >> 4;          // n / K
    int r = n & 15;          // n % K

    int j = k * (N / K_NN) + g;
    int a = midx[j * K_NN + r];
    float2 cp = ((const float2*)ch2)[a];
    float cx = a0 + a1 * cp.y + cp.x * (a2 + a3 * cp.y);
    float cy = b0 + b1 * cp.y + cp.x * (b2 + b3 * cp.y);
    float dx = ch1[2 * n + 0] - cx;
    float dy = ch1[2 * n + 1] - cy;
    float term = expf(-(dx * dx + dy * dy) * (1.0f / 4.5f));

    // sum over k within each 16-lane group
#pragma unroll
    for (int off = 8; off; off >>= 1) term += __shfl_down(term, off, 16);

    float v = 0.0f;
    if (k == 0) {
        float expD = term / (float)N;
        v = (expD != 0.0f) ? logf(expD) : 0.0f;
    }
#pragma unroll
    for (int off = 32; off; off >>= 1) v += __shfl_down(v, off, 64);

    __shared__ float red[4];
    int lane = threadIdx.x & 63;
    int wv = threadIdx.x >> 6;
    if (lane == 0) red[wv] = v;
    __syncthreads();
    if (threadIdx.x == 0)
        atomicAdd(out, -(red[0] + red[1] + red[2] + red[3]));
}

// ---------------------------------------------------------------------------
extern "C" void kernel_launch(void* const* d_in, const int* in_sizes, int n_in,
                              void* d_out, int out_size, void* d_ws, size_t ws_size,
                              hipStream_t stream) {
    const float* ch1 = (const float*)d_in[0];
    const float* ch2 = (const float*)d_in[1];
    const float* M1  = (const float*)d_in[2];
    const float* M2  = (const float*)d_in[3];
    float* out = (float*)d_out;
    const int N = in_sizes[0] / 2;   // 8192

    int* midx = (int*)d_ws;          // 512 KB

    k1_knn<<<N / WPB, 256, 0, stream>>>(ch1, ch2, M1, M2, midx, out);

    k3_final<<<(N * K_NN) / 256, 256, 0, stream>>>(ch1, ch2, M1, M2, midx, out, N);
}

// Round 5
// 101.698 us; speedup vs baseline: 3.7406x; 1.0664x over previous
//
#include <hip/hip_runtime.h>
#include <math.h>
#include <stdint.h>

#define K_NN 16
#define NPTS 8192
#define WPB 16             // waves (= queries) per block; block = 1024 threads

// ---------------------------------------------------------------------------
// k1: wave-cooperative KNN, one wave per query, whole candidate set in LDS.
// Block = 1024 threads stages all 8192 poly-transformed points (64 KB) once;
// afterwards each wave scans independently -- zero mid-scan barriers.
// Top-16 = lane-distributed sorted packed keys (dist_bits & ~0x1FFF) | idx
// in lanes 0-15 (every 16-lane DPP row keeps an identical copy). Per step a
// wave scores 128 candidates (float4 = 2 pts/lane, next step's read
// prefetched), ballots vs wave-uniform kth, and a uniform scalar loop
// processes events; after each insert the ballot is refreshed so stale
// events are pruned (m &= m-1 first keeps termination). Packing gives exact
// jax.lax.top_k (dist, idx) tie order modulo 2^-10-relative dist truncation;
// k3 recomputes exact distances of the selected indices.
// ---------------------------------------------------------------------------
__global__ __launch_bounds__(1024) void k1_knn(const float* __restrict__ ch1,
                                               const float* __restrict__ ch2,
                                               const float* __restrict__ M1,
                                               const float* __restrict__ M2,
                                               int* __restrict__ midx,
                                               float* __restrict__ out) {
    __shared__ float2 sh[NPTS];        // 64 KB: entire transformed ch2

    const int tid  = threadIdx.x;
    const int lane = tid & 63;
    const int w    = tid >> 6;
    const int qg   = blockIdx.x * WPB + w;

    if (blockIdx.x == 0 && tid == 0) out[0] = 0.0f;   // k3 atomics start from 0

    const float q0 = ch1[2 * qg + 0];
    const float q1 = ch1[2 * qg + 1];

    const float a0 = M1[0], a1 = M1[1], a2 = M1[2], a3 = M1[3];
    const float b0 = M2[0], b1 = M2[1], b2 = M2[2], b3 = M2[3];

    const float4* __restrict__ g4 = (const float4*)ch2;

    // stage everything once (poly fused): 4096 float4 / 1024 threads
#pragma unroll
    for (int e = 0; e < (NPTS / 2) / 1024; ++e) {
        float4 v = g4[e * 1024 + tid];
        float px0 = a0 + a1 * v.y + v.x * (a2 + a3 * v.y);
        float py0 = b0 + b1 * v.y + v.x * (b2 + b3 * v.y);
        float px1 = a0 + a1 * v.w + v.z * (a2 + a3 * v.w);
        float py1 = b0 + b1 * v.w + v.z * (b2 + b3 * v.w);
        ((float4*)sh)[e * 1024 + tid] = make_float4(px0, py0, px1, py1);
    }
    __syncthreads();

    unsigned key = 0xFFFFFFFFu;        // lanes 0-15: sorted top-16 packed keys
    unsigned kth = 0xFFFFFFFFu;        // wave-uniform copy of lane 15's key

    const float4* s4 = (const float4*)sh;
    float4 c = s4[lane];               // prefetch step 0

    for (int t = 0; t < NPTS / 128; ++t) {
        float4 cn = s4[(((t + 1) & 63) * 64) + lane];   // prefetch next (wraps)
        int base = (t * 64 + lane) * 2;
        float dx0 = q0 - c.x, dy0 = q1 - c.y;
        float dx1 = q0 - c.z, dy1 = q1 - c.w;
        float nd0 = dx0 * dx0 + dy0 * dy0;
        float nd1 = dx1 * dx1 + dy1 * dy1;
        unsigned nk0 = (__float_as_uint(nd0) & 0xFFFFE000u) | (unsigned)base;
        unsigned nk1 = (__float_as_uint(nd1) & 0xFFFFE000u) | (unsigned)(base + 1);

        unsigned long long m = __ballot(nk0 < kth);
        while (m) {
            int l = __ffsll(m) - 1;
            unsigned snk = (unsigned)__builtin_amdgcn_readlane((int)nk0, l);
            unsigned up = (unsigned)__builtin_amdgcn_update_dpp(
                0, (int)key, 0x111, 0xF, 0xF, false);   // row_shr:1
            bool c1 = snk < key;
            unsigned nv = (snk < up) ? up : snk;
            key = c1 ? nv : key;
            kth = (unsigned)__builtin_amdgcn_readlane((int)key, 15);
            m &= m - 1;                    // clear processed bit (termination)
            m &= __ballot(nk0 < kth);      // prune now-stale events
        }

        m = __ballot(nk1 < kth);           // balloted with post-m0 kth
        while (m) {
            int l = __ffsll(m) - 1;
            unsigned snk = (unsigned)__builtin_amdgcn_readlane((int)nk1, l);
            unsigned up = (unsigned)__builtin_amdgcn_update_dpp(
                0, (int)key, 0x111, 0xF, 0xF, false);
            bool c1 = snk < key;
            unsigned nv = (snk < up) ? up : snk;
            key = c1 ? nv : key;
            kth = (unsigned)__builtin_amdgcn_readlane((int)key, 15);
            m &= m - 1;
            m &= __ballot(nk1 < kth);
        }

        c = cn;
    }

    if (lane < K_NN)
        midx[qg * K_NN + lane] = (int)(key & 0x1FFFu);
}

// ---------------------------------------------------------------------------
// k3: scrambled gather + log-sum-exp. One thread per (n,k) pair (131072).
// A[k,n] = midx[(k*(N/K) + n/K)*K + (n%K)]; distance recomputed exactly with
// the polynomial applied on the fly.
// ---------------------------------------------------------------------------
__global__ __launch_bounds__(256) void k3_final(const float* __restrict__ ch1,
                                                const float* __restrict__ ch2,
                                                const float* __restrict__ M1,
                                                const float* __restrict__ M2,
                                                const int* __restrict__ midx,
                                                float* __restrict__ out, int N) {
    const float a0 = M1[0], a1 = M1[1], a2 = M1[2], a3 = M1[3];
    const float b0 = M2[0], b1 = M2[1], b2 = M2[2], b3 = M2[3];

    int t = blockIdx.x * 256 + threadIdx.x;   // [0, N*K)
    int n = t >> 4;
    int k = t & 15;
    int g = n >> 4;          // n / K
    int r = n & 15;          // n % K

    int j = k * (N / K_NN) + g;
    int a = midx[j * K_NN + r];
    float2 cp = ((const float2*)ch2)[a];
    float cx = a0 + a1 * cp.y + cp.x * (a2 + a3 * cp.y);
    float cy = b0 + b1 * cp.y + cp.x * (b2 + b3 * cp.y);
    float dx = ch1[2 * n + 0] - cx;
    float dy = ch1[2 * n + 1] - cy;
    float term = expf(-(dx * dx + dy * dy) * (1.0f / 4.5f));

    // sum over k within each 16-lane group
#pragma unroll
    for (int off = 8; off; off >>= 1) term += __shfl_down(term, off, 16);

    float v = 0.0f;
    if (k == 0) {
        float expD = term / (float)N;
        v = (expD != 0.0f) ? logf(expD) : 0.0f;
    }
#pragma unroll
    for (int off = 32; off; off >>= 1) v += __shfl_down(v, off, 64);

    __shared__ float red[4];
    int lane = threadIdx.x & 63;
    int wv = threadIdx.x >> 6;
    if (lane == 0) red[wv] = v;
    __syncthreads();
    if (threadIdx.x == 0)
        atomicAdd(out, -(red[0] + red[1] + red[2] + red[3]));
}

// ---------------------------------------------------------------------------
extern "C" void kernel_launch(void* const* d_in, const int* in_sizes, int n_in,
                              void* d_out, int out_size, void* d_ws, size_t ws_size,
                              hipStream_t stream) {
    const float* ch1 = (const float*)d_in[0];
    const float* ch2 = (const float*)d_in[1];
    const float* M1  = (const float*)d_in[2];
    const float* M2  = (const float*)d_in[3];
    float* out = (float*)d_out;
    const int N = in_sizes[0] / 2;   // 8192

    int* midx = (int*)d_ws;          // 512 KB

    k1_knn<<<N / WPB, 1024, 0, stream>>>(ch1, ch2, M1, M2, midx, out);

    k3_final<<<(N * K_NN) / 256, 256, 0, stream>>>(ch1, ch2, M1, M2, midx, out, N);
}

// Round 6
// 95.977 us; speedup vs baseline: 3.9636x; 1.0596x over previous
//
#include <hip/hip_runtime.h>
#include <math.h>
#include <stdint.h>

#define K_NN 16
#define NPTS 8192
#define HALF (NPTS / 2)    // 4096 points staged per pass (32 KB LDS)
#define WPB 16             // waves (= queries) per block; block = 1024 threads

// ---------------------------------------------------------------------------
// k1: wave-cooperative KNN, one wave per query, candidate set in LDS in two
// 32 KB passes (2 blocks/CU co-resident -> 32 waves/CU = 100% occupancy).
// Top-16 = lane-distributed sorted packed keys (dist_bits & ~0x1FFF) | idx
// in lanes 0-15 (each 16-lane DPP row keeps an identical copy). Per step a
// wave scores 128 candidates (float4 = 2 pts/lane, next read prefetched),
// ballots vs wave-uniform kth, and a uniform scalar loop processes events.
// After each insert the ballot is refreshed (m &= m-1 first keeps
// termination), so surviving bits are always fresh -> no per-event recheck
// needed (stale inserts would self-reject regardless). Packing gives exact
// jax.lax.top_k (dist, idx) tie order modulo 2^-10-relative dist truncation;
// k3 recomputes exact distances of the selected indices.
// ---------------------------------------------------------------------------
__global__ __launch_bounds__(1024) void k1_knn(const float* __restrict__ ch1,
                                               const float* __restrict__ ch2,
                                               const float* __restrict__ M1,
                                               const float* __restrict__ M2,
                                               int* __restrict__ midx,
                                               float* __restrict__ out) {
    __shared__ float2 sh[HALF];        // 32 KB: half the transformed ch2

    const int tid  = threadIdx.x;
    const int lane = tid & 63;
    const int w    = tid >> 6;
    const int qg   = blockIdx.x * WPB + w;

    if (blockIdx.x == 0 && tid == 0) out[0] = 0.0f;   // k3 atomics start from 0

    const float q0 = ch1[2 * qg + 0];
    const float q1 = ch1[2 * qg + 1];

    const float a0 = M1[0], a1 = M1[1], a2 = M1[2], a3 = M1[3];
    const float b0 = M2[0], b1 = M2[1], b2 = M2[2], b3 = M2[3];

    const float4* __restrict__ g4 = (const float4*)ch2;

    unsigned key = 0xFFFFFFFFu;        // lanes 0-15: sorted top-16 packed keys
    unsigned kth = 0xFFFFFFFFu;        // wave-uniform copy of lane 15's key

    for (int pass = 0; pass < 2; ++pass) {
        __syncthreads();               // protect sh against previous pass scan
        // stage 4096 points (poly fused): 2048 float4 / 1024 threads
#pragma unroll
        for (int e = 0; e < (HALF / 2) / 1024; ++e) {
            float4 v = g4[pass * (HALF / 2) + e * 1024 + tid];
            float px0 = a0 + a1 * v.y + v.x * (a2 + a3 * v.y);
            float py0 = b0 + b1 * v.y + v.x * (b2 + b3 * v.y);
            float px1 = a0 + a1 * v.w + v.z * (a2 + a3 * v.w);
            float py1 = b0 + b1 * v.w + v.z * (b2 + b3 * v.w);
            ((float4*)sh)[e * 1024 + tid] = make_float4(px0, py0, px1, py1);
        }
        __syncthreads();

        const float4* s4 = (const float4*)sh;
        float4 c = s4[lane];           // prefetch step 0 of this pass

        for (int t = 0; t < HALF / 128; ++t) {
            float4 cn = s4[(((t + 1) & (HALF / 128 - 1)) * 64) + lane];
            int base = pass * HALF + (t * 64 + lane) * 2;
            float dx0 = q0 - c.x, dy0 = q1 - c.y;
            float dx1 = q0 - c.z, dy1 = q1 - c.w;
            float nd0 = dx0 * dx0 + dy0 * dy0;
            float nd1 = dx1 * dx1 + dy1 * dy1;
            unsigned nk0 = (__float_as_uint(nd0) & 0xFFFFE000u) | (unsigned)base;
            unsigned nk1 = (__float_as_uint(nd1) & 0xFFFFE000u) | (unsigned)(base + 1);

            unsigned long long m = __ballot(nk0 < kth);
            while (m) {
                int l = __ffsll(m) - 1;
                unsigned snk = (unsigned)__builtin_amdgcn_readlane((int)nk0, l);
                unsigned up = (unsigned)__builtin_amdgcn_update_dpp(
                    0, (int)key, 0x111, 0xF, 0xF, false);   // row_shr:1
                bool c1 = snk < key;
                unsigned nv = (snk < up) ? up : snk;
                key = c1 ? nv : key;
                kth = (unsigned)__builtin_amdgcn_readlane((int)key, 15);
                m &= m - 1;                    // clear processed bit (termination)
                m &= __ballot(nk0 < kth);      // prune now-stale events
            }

            m = __ballot(nk1 < kth);
            while (m) {
                int l = __ffsll(m) - 1;
                unsigned snk = (unsigned)__builtin_amdgcn_readlane((int)nk1, l);
                unsigned up = (unsigned)__builtin_amdgcn_update_dpp(
                    0, (int)key, 0x111, 0xF, 0xF, false);
                bool c1 = snk < key;
                unsigned nv = (snk < up) ? up : snk;
                key = c1 ? nv : key;
                kth = (unsigned)__builtin_amdgcn_readlane((int)key, 15);
                m &= m - 1;
                m &= __ballot(nk1 < kth);
            }

            c = cn;
        }
    }

    if (lane < K_NN)
        midx[qg * K_NN + lane] = (int)(key & 0x1FFFu);
}

// ---------------------------------------------------------------------------
// k3: scrambled gather + log-sum-exp. One thread per (n,k) pair (131072).
// A[k,n] = midx[(k*(N/K) + n/K)*K + (n%K)]; distance recomputed exactly with
// the polynomial applied on the fly. 1024-thread blocks -> 128 atomics total.
// ---------------------------------------------------------------------------
__global__ __launch_bounds__(1024) void k3_final(const float* __restrict__ ch1,
                                                 const float* __restrict__ ch2,
                                                 const float* __restrict__ M1,
                                                 const float* __restrict__ M2,
                                                 const int* __restrict__ midx,
                                                 float* __restrict__ out, int N) {
    const float a0 = M1[0], a1 = M1[1], a2 = M1[2], a3 = M1[3];
    const float b0 = M2[0], b1 = M2[1], b2 = M2[2], b3 = M2[3];

    int t = blockIdx.x * 1024 + threadIdx.x;  // [0, N*K)
    int n = t >> 4;
    int k = t & 15;
    int g = n >> 4;          // n / K
    int r = n & 15;          // n % K

    int j = k * (N / K_NN) + g;
    int a = midx[j * K_NN + r];
    float2 cp = ((const float2*)ch2)[a];
    float cx = a0 + a1 * cp.y + cp.x * (a2 + a3 * cp.y);
    float cy = b0 + b1 * cp.y + cp.x * (b2 + b3 * cp.y);
    float dx = ch1[2 * n + 0] - cx;
    float dy = ch1[2 * n + 1] - cy;
    float term = expf(-(dx * dx + dy * dy) * (1.0f / 4.5f));

    // sum over k within each 16-lane group
#pragma unroll
    for (int off = 8; off; off >>= 1) term += __shfl_down(term, off, 16);

    float v = 0.0f;
    if (k == 0) {
        float expD = term / (float)N;
        v = (expD != 0.0f) ? logf(expD) : 0.0f;
    }
#pragma unroll
    for (int off = 32; off; off >>= 1) v += __shfl_down(v, off, 64);

    __shared__ float red[16];
    int lane = threadIdx.x & 63;
    int wv = threadIdx.x >> 6;
    if (lane == 0) red[wv] = v;
    __syncthreads();
    if (threadIdx.x == 0) {
        float s = 0.0f;
#pragma unroll
        for (int i = 0; i < 16; ++i) s += red[i];
        atomicAdd(out, -s);
    }
}

// ---------------------------------------------------------------------------
extern "C" void kernel_launch(void* const* d_in, const int* in_sizes, int n_in,
                              void* d_out, int out_size, void* d_ws, size_t ws_size,
                              hipStream_t stream) {
    const float* ch1 = (const float*)d_in[0];
    const float* ch2 = (const float*)d_in[1];
    const float* M1  = (const float*)d_in[2];
    const float* M2  = (const float*)d_in[3];
    float* out = (float*)d_out;
    const int N = in_sizes[0] / 2;   // 8192

    int* midx = (int*)d_ws;          // 512 KB

    k1_knn<<<N / WPB, 1024, 0, stream>>>(ch1, ch2, M1, M2, midx, out);

    k3_final<<<(N * K_NN) / 1024, 1024, 0, stream>>>(ch1, ch2, M1, M2, midx, out, N);
}